// Round 21
// baseline (120.611 us; speedup 1.0000x reference)
//
#include <hip/hip_runtime.h>

#define NN   1024
#define TT   12
#define CC   64
#define DD   64
#define HH   2
#define KK   3
#define ETOT 17408           // E (16384) + N self loops
#define BT   48              // B*T
#define BTH  96              // B*T*H
#define HD   128             // H*D
#define NODES (KK * NN + 1)  // +1 sentinel pad node (feat=0, el=-inf)
#define PADN  (KK * NN)
#define CSR_CAP (KK * ETOT + 12 * NN)   // segments padded to x4 (= 64512)
#define LOG2E 1.44269504f
#define MT   128                         // feat GEMM M-tile
#define NBLK (NN * BT / MT)              // 384 M-tiles
#define EDGE_BLOCKS ((KK * ETOT + 255) / 256)   // 204
#define FEAT_BLOCKS (KK * NBLK)                 // 1152
#define NSL  12                          // slices: (btg8 0..5) x (h 0..1)
#define RUNCAP 144                       // max combined padded run per n (~86 actual)

typedef __attribute__((ext_vector_type(8))) short s8v;    // 8 bf16
typedef __attribute__((ext_vector_type(4))) float f4v;    // 4 f32 acc

__device__ __forceinline__ float bf_lo(unsigned int u) {
    return __uint_as_float(u << 16);
}
__device__ __forceinline__ float bf_hi(unsigned int u) {
    return __uint_as_float(u & 0xFFFF0000u);
}
__device__ __forceinline__ unsigned short f2bf(float f) {
    unsigned int u = __float_as_uint(f);
    u += 0x7FFFu + ((u >> 16) & 1u);      // round-to-nearest-even
    return (unsigned short)(u >> 16);
}
__device__ __forceinline__ unsigned int pack2(float a, float b) {
    return (unsigned int)f2bf(a) | ((unsigned int)f2bf(b) << 16);
}
__device__ __forceinline__ float rlf(float v, int lane) {
    return __int_as_float(__builtin_amdgcn_readlane(__float_as_int(v), lane));
}

// ---------------- aux: count (blocks 0..203) + prep_alc + pad-init ----------
__global__ __launch_bounds__(256) void aux_kernel(
    const int* __restrict__ dst_idx, int* __restrict__ counts,
    const float* __restrict__ fc_w, const float* __restrict__ attn_l,
    const float* __restrict__ attn_r, float* __restrict__ alc, float* __restrict__ arc,
    uint4* __restrict__ featp, float* __restrict__ elp)
{
    int bid = blockIdx.x;
    int t = threadIdx.x;
    if (bid < EDGE_BLOCKS) {
        int tid = bid * 256 + t;
        if (tid < KK * ETOT) {
            int k = tid / ETOT;
            atomicAdd(&counts[k * NN + dst_idx[tid]], 1);
        }
    } else {
        for (int item = t; item < KK * HH * CC; item += 256) {   // prep_alc
            int kh = item >> 6, c = item & 63;
            int k = kh >> 1, h = kh & 1;
            float sl = 0.f, sr = 0.f;
            #pragma unroll
            for (int dd = 0; dd < 64; ++dd) {
                float wv = fc_w[k * CC * HD + c * HD + h * 64 + dd];
                sl = fmaf(wv, attn_l[k * HD + h * 64 + dd], sl);
                sr = fmaf(wv, attn_r[k * HD + h * 64 + dd], sr);
            }
            alc[item] = sl * LOG2E;
            arc[item] = sr * LOG2E;
        }
        for (int item = t; item < NSL * 64; item += 256)         // feat pad node
            featp[((size_t)(item >> 6) * NODES + PADN) * 64 + (item & 63)] =
                make_uint4(0u, 0u, 0u, 0u);
        for (int item = t; item < NSL * 8; item += 256)          // elp pad node
            elp[((size_t)(item >> 3) * NODES + PADN) * 8 + (item & 7)] = -1e30f;
    }
}

// ---------------- CSR scan (per-(k,n) segments, padded to 4) ----------------
__global__ __launch_bounds__(1024) void scan_kernel(
    const int* __restrict__ counts,
    int4* __restrict__ segs, int* __restrict__ cursor, int* __restrict__ csr_comb)
{
    int n = threadIdx.x;
    int c0 = counts[n], c1 = counts[NN + n], c2 = counts[2 * NN + n];
    int p0 = (c0 + 3) & ~3, p1 = (c1 + 3) & ~3, p2 = (c2 + 3) & ~3;
    int tot = p0 + p1 + p2;
    __shared__ int buf[NN];
    buf[n] = tot;
    __syncthreads();
    for (int off = 1; off < NN; off <<= 1) {
        int v = (n >= off) ? buf[n - off] : 0;
        __syncthreads();
        buf[n] += v;
        __syncthreads();
    }
    int excl = buf[n] - tot;
    int4 sg;
    sg.x = excl; sg.y = excl + p0; sg.z = excl + p0 + p1; sg.w = excl + tot;
    segs[n] = sg;
    cursor[n] = sg.x;
    cursor[NN + n] = sg.y;
    cursor[2 * NN + n] = sg.z;
    for (int j = sg.x + c0; j < sg.y; ++j) csr_comb[j] = PADN;
    for (int j = sg.y + c1; j < sg.z; ++j) csr_comb[j] = PADN;
    for (int j = sg.z + c2; j < sg.w; ++j) csr_comb[j] = PADN;
}

// ---------------- feat = x @ fc_w via bf16 MFMA (XCD-aware, k inner) --------
__global__ __launch_bounds__(256) void feat_kernel(
    const float* __restrict__ x, const float* __restrict__ fc_w,
    uint4* __restrict__ featp)
{
    int jj = ((int)blockIdx.x & 7) * (FEAT_BLOCKS / 8) + ((int)blockIdx.x >> 3);
    int mt = jj / KK;
    int k  = jj - mt * KK;
    int m0 = mt * MT;
    int t  = threadIdx.x;
    int w  = t >> 6, l = t & 63;

    __shared__ __align__(16) unsigned short As[128 * 64];  // 16 KB
    __shared__ __align__(16) unsigned short Ws[128 * 64];  // 16 KB

    #pragma unroll
    for (int rep = 0; rep < 4; ++rep) {
        int gid = t + 256 * rep;       // 0..1023
        int row = gid >> 3, g = gid & 7;
        int m = m0 + row;
        int n = m / BT, bt = m - n * BT;
        int b = bt / TT, tt2 = bt - b * TT;
        const float* xr = &x[(((size_t)b * NN + n) * TT + tt2) * CC + g * 8];
        float4 v0 = *(const float4*)xr;
        float4 v1 = *(const float4*)(xr + 4);
        uint4 pk = { pack2(v0.x, v0.y), pack2(v0.z, v0.w),
                     pack2(v1.x, v1.y), pack2(v1.z, v1.w) };
        *(uint4*)((char*)As + row * 128 + ((g ^ (row & 7)) << 4)) = pk;
    }
    #pragma unroll
    for (int rep = 0; rep < 4; ++rep) {
        int gid = t + 256 * rep;
        int e = gid & 127, g = gid >> 7;
        float v[8];
        #pragma unroll
        for (int jv = 0; jv < 8; ++jv)
            v[jv] = fc_w[(size_t)k * CC * HD + (g * 8 + jv) * HD + e];
        uint4 pk = { pack2(v[0], v[1]), pack2(v[2], v[3]),
                     pack2(v[4], v[5]), pack2(v[6], v[7]) };
        *(uint4*)((char*)Ws + e * 128 + ((g ^ (e & 7)) << 4)) = pk;
    }
    __syncthreads();

    int Mw = (w & 1) * 64;
    int Nw = (w >> 1) * 64;
    int rsel = l & 15, ksel = l >> 4;

    f4v acc[4][4];
    #pragma unroll
    for (int mi = 0; mi < 4; ++mi)
        #pragma unroll
        for (int nf = 0; nf < 4; ++nf)
            acc[mi][nf] = (f4v){0.f, 0.f, 0.f, 0.f};

    s8v af[4][2], bf[4][2];
    #pragma unroll
    for (int mi = 0; mi < 4; ++mi)
        #pragma unroll
        for (int ks = 0; ks < 2; ++ks) {
            int row = Mw + mi * 16 + rsel;
            int g = ks * 4 + ksel;
            af[mi][ks] = *(const s8v*)((const char*)As + row * 128 + ((g ^ (row & 7)) << 4));
        }
    #pragma unroll
    for (int nf = 0; nf < 4; ++nf)
        #pragma unroll
        for (int ks = 0; ks < 2; ++ks) {
            int e = Nw + nf * 16 + rsel;
            int g = ks * 4 + ksel;
            bf[nf][ks] = *(const s8v*)((const char*)Ws + e * 128 + ((g ^ (e & 7)) << 4));
        }

    #pragma unroll
    for (int mi = 0; mi < 4; ++mi)
        #pragma unroll
        for (int nf = 0; nf < 4; ++nf) {
            acc[mi][nf] = __builtin_amdgcn_mfma_f32_16x16x32_bf16(
                af[mi][0], bf[nf][0], acc[mi][nf], 0, 0, 0);
            acc[mi][nf] = __builtin_amdgcn_mfma_f32_16x16x32_bf16(
                af[mi][1], bf[nf][1], acc[mi][nf], 0, 0, 0);
        }

    // epilogue: combine partner frags (rows +0..3 / +4..7) into bt-octet
    int i0 = (l >> 4) * 4;
    bool writer = ((l >> 4) & 1) == 0;     // i0 in {0, 8}
    #pragma unroll
    for (int mi = 0; mi < 4; ++mi) {
        int m = m0 + Mw + mi * 16 + i0;    // octet base row for writer lanes
        int n = m / BT, bt = m - n * BT;
        #pragma unroll
        for (int nf = 0; nf < 4; ++nf) {
            uint2 o = { pack2(acc[mi][nf][0], acc[mi][nf][1]),
                        pack2(acc[mi][nf][2], acc[mi][nf][3]) };
            unsigned int px = (unsigned int)__shfl_xor((int)o.x, 16, 64);
            unsigned int py = (unsigned int)__shfl_xor((int)o.y, 16, 64);
            if (writer) {
                int e = Nw + nf * 16 + (l & 15);
                int h = e >> 6, d = e & 63;
                int s = ((bt >> 3) << 1) + h;
                featp[((size_t)s * NODES + k * NN + n) * 64 + d] =
                    make_uint4(o.x, o.y, px, py);
            }
        }
    }
}

// ---------------- side: scatter (0..203) | elr (204..1227) ------------------
__global__ __launch_bounds__(256) void side_kernel(
    const int* __restrict__ src_idx, const int* __restrict__ dst_idx,
    int* __restrict__ cursor, int* __restrict__ csr_comb,
    const float* __restrict__ x,
    const float* __restrict__ alc, const float* __restrict__ arc,
    float* __restrict__ elp, float* __restrict__ er)
{
    int bid = blockIdx.x;
    int t = threadIdx.x;

    if (bid < EDGE_BLOCKS) {
        int tid = bid * 256 + t;
        if (tid < KK * ETOT) {
            int k = tid / ETOT;
            int pos = atomicAdd(&cursor[k * NN + dst_idx[tid]], 1);
            csr_comb[pos] = k * NN + src_idx[tid];
        }
        return;
    }

    // elr: el/er tiny GEMV per n
    __shared__ float x_lds[BT * CC];       // 12 KB
    __shared__ float cl[KK * HH * CC];     // 1.5 KB
    __shared__ float cr[KK * HH * CC];     // 1.5 KB
    int n = bid - EDGE_BLOCKS;

    for (int i = t; i < BT * CC; i += 256) {
        int bt = i >> 6, c = i & 63;
        int b = bt / TT, tt = bt - b * TT;
        x_lds[i] = x[(((size_t)b * NN + n) * TT + tt) * CC + c];
    }
    for (int i = t; i < KK * HH * CC; i += 256) { cl[i] = alc[i]; cr[i] = arc[i]; }
    __syncthreads();

    if (t < BTH) {
        int hh = t / BT, bt = t - hh * BT;
        #pragma unroll
        for (int k = 0; k < KK; ++k) {
            const float* alp = &cl[(k * HH + hh) * CC];
            const float* arp = &cr[(k * HH + hh) * CC];
            float sl = 0.f, sr = 0.f;
            #pragma unroll
            for (int cc = 0; cc < CC; ++cc) {
                int c = (cc + bt) & 63;        // stagger: conflict-free
                float xv = x_lds[bt * CC + c];
                sl = fmaf(xv, alp[c], sl);
                sr = fmaf(xv, arp[c], sr);
            }
            int s = ((bt >> 3) << 1) + hh;
            elp[((size_t)s * NODES + k * NN + n) * 8 + (bt & 7)] = sl;
            er[((size_t)(k * NN + n)) * BTH + t] = sr;
        }
    }
}

// ---------------- agg: fused softmax + gather-sum, pipelined phase2 ---------
#define EFMA(F, LO, HI)                                        \
    r0 = fmaf((LO).x, bf_lo((F).x), r0);                       \
    r1 = fmaf((LO).y, bf_hi((F).x), r1);                       \
    r2 = fmaf((LO).z, bf_lo((F).y), r2);                       \
    r3 = fmaf((LO).w, bf_hi((F).y), r3);                       \
    r4 = fmaf((HI).x, bf_lo((F).z), r4);                       \
    r5 = fmaf((HI).y, bf_hi((F).z), r5);                       \
    r6 = fmaf((HI).z, bf_lo((F).w), r6);                       \
    r7 = fmaf((HI).w, bf_hi((F).w), r7);

#define PHASE1(JB, JE, KIDX, SCLO, SCHI) {                                     \
    int jb = (JB), je = (JE);                                                  \
    float erv = er[((size_t)((KIDX) * NN + n)) * BTH + h * BT + btg8 * 8 + btq];\
    float ss = 0.f;                                                            \
    for (int j0 = jb; j0 < je; j0 += 8) {                                      \
        int jjq = j0 + joff;                                                   \
        float a = 0.f;                                                         \
        if (jjq < je) {                                                        \
            int idx = csr_comb[jjq];                                           \
            float ev = elp[sbase8 + (size_t)idx * 8 + btq] + erv;              \
            ev = fmaxf(ev, ev * 0.2f);                                         \
            a = __builtin_amdgcn_exp2f(ev);                                    \
            alds[w][jjq - base0][btq] = a;                                     \
        }                                                                      \
        ss += a;                                                               \
    }                                                                          \
    ss += __shfl_xor(ss, 8, 64);                                               \
    ss += __shfl_xor(ss, 16, 64);                                              \
    ss += __shfl_xor(ss, 32, 64);                                              \
    float wk_ = weight[KIDX];                                                  \
    SCLO = make_float4(wk_ * __builtin_amdgcn_rcpf(rlf(ss, 0)),                \
                       wk_ * __builtin_amdgcn_rcpf(rlf(ss, 1)),                \
                       wk_ * __builtin_amdgcn_rcpf(rlf(ss, 2)),                \
                       wk_ * __builtin_amdgcn_rcpf(rlf(ss, 3)));               \
    SCHI = make_float4(wk_ * __builtin_amdgcn_rcpf(rlf(ss, 4)),                \
                       wk_ * __builtin_amdgcn_rcpf(rlf(ss, 5)),                \
                       wk_ * __builtin_amdgcn_rcpf(rlf(ss, 6)),                \
                       wk_ * __builtin_amdgcn_rcpf(rlf(ss, 7))); }

// 2-stage software pipeline: prefetch chunk i+1's csr+gathers before FMA-ing
// chunk i, so each 128-op FMA block covers the next chunk's load latency.
#define PHASE2(JB, JE, SCLO, SCHI) {                                           \
    int jb = __builtin_amdgcn_readfirstlane(JB);                               \
    int je = __builtin_amdgcn_readfirstlane(JE);                               \
    float r0=0.f,r1=0.f,r2=0.f,r3=0.f,r4=0.f,r5=0.f,r6=0.f,r7=0.f;             \
    int4 iC = *(const int4*)&csr_comb[jb];                                     \
    uint4 fC0 = fb[(size_t)__builtin_amdgcn_readfirstlane(iC.x) * 64];         \
    uint4 fC1 = fb[(size_t)__builtin_amdgcn_readfirstlane(iC.y) * 64];         \
    uint4 fC2 = fb[(size_t)__builtin_amdgcn_readfirstlane(iC.z) * 64];         \
    uint4 fC3 = fb[(size_t)__builtin_amdgcn_readfirstlane(iC.w) * 64];         \
    for (int jjq = jb; jjq < je; jjq += 4) {                                   \
        uint4 f0 = fC0, f1 = fC1, f2 = fC2, f3 = fC3;                          \
        int jn = jjq + 4;                                                      \
        if (jn < je) {                                                         \
            iC = *(const int4*)&csr_comb[jn];                                  \
            fC0 = fb[(size_t)__builtin_amdgcn_readfirstlane(iC.x) * 64];       \
            fC1 = fb[(size_t)__builtin_amdgcn_readfirstlane(iC.y) * 64];       \
            fC2 = fb[(size_t)__builtin_amdgcn_readfirstlane(iC.z) * 64];       \
            fC3 = fb[(size_t)__builtin_amdgcn_readfirstlane(iC.w) * 64];       \
        }                                                                      \
        float4 L0 = *(const float4*)&alds[w][jjq - base0 + 0][0];              \
        float4 H0 = *(const float4*)&alds[w][jjq - base0 + 0][4];              \
        float4 L1 = *(const float4*)&alds[w][jjq - base0 + 1][0];              \
        float4 H1 = *(const float4*)&alds[w][jjq - base0 + 1][4];              \
        float4 L2 = *(const float4*)&alds[w][jjq - base0 + 2][0];              \
        float4 H2 = *(const float4*)&alds[w][jjq - base0 + 2][4];              \
        float4 L3 = *(const float4*)&alds[w][jjq - base0 + 3][0];              \
        float4 H3 = *(const float4*)&alds[w][jjq - base0 + 3][4];              \
        EFMA(f0, L0, H0); EFMA(f1, L1, H1);                                    \
        EFMA(f2, L2, H2); EFMA(f3, L3, H3);                                    \
    }                                                                          \
    acc0 = fmaf(r0, (SCLO).x, acc0); acc1 = fmaf(r1, (SCLO).y, acc1);          \
    acc2 = fmaf(r2, (SCLO).z, acc2); acc3 = fmaf(r3, (SCLO).w, acc3);          \
    acc4 = fmaf(r4, (SCHI).x, acc4); acc5 = fmaf(r5, (SCHI).y, acc5);          \
    acc6 = fmaf(r6, (SCHI).z, acc6); acc7 = fmaf(r7, (SCHI).w, acc7); }

__global__ __launch_bounds__(256) void agg_kernel(
    const uint4* __restrict__ featp,
    const float* __restrict__ elp,
    const float* __restrict__ er,
    const int4* __restrict__ segs, const int* __restrict__ csr_comb,
    const float* __restrict__ gat_bias, const float* __restrict__ weight,
    unsigned short* __restrict__ gatb)   // [n*BT+bt][HD] bf16
{
    int xcd = (int)blockIdx.x & 7;
    int q   = (int)blockIdx.x >> 3;      // 0..383
    int j   = q + 384 * xcd;             // 0..3071
    int s   = j >> 8;                    // 0..11
    int g   = j & 255;
    int w = threadIdx.x >> 6;
    int l = threadIdx.x & 63;
    int n = g * 4 + w;
    int btg8 = s >> 1, h = s & 1;
    int e = h * 64 + l;

    __shared__ __align__(16) float alds[4][RUNCAP][8];   // 18.4 KB

    const uint4* fb = featp + (size_t)s * NODES * 64 + l;
    size_t sbase8 = (size_t)s * NODES * 8;
    int4 sg = segs[n];
    int base0 = __builtin_amdgcn_readfirstlane(sg.x);

    int joff = l >> 3, btq = l & 7;
    float acc0=0.f,acc1=0.f,acc2=0.f,acc3=0.f,acc4=0.f,acc5=0.f,acc6=0.f,acc7=0.f;
    float4 sclo, schi;

    PHASE1(sg.x, sg.y, 0, sclo, schi)
    PHASE2(sg.x, sg.y, sclo, schi)
    PHASE1(sg.y, sg.z, 1, sclo, schi)
    PHASE2(sg.y, sg.z, sclo, schi)
    PHASE1(sg.z, sg.w, 2, sclo, schi)
    PHASE2(sg.z, sg.w, sclo, schi)

    float wb = weight[0] * gat_bias[e] + weight[1] * gat_bias[HD + e]
             + weight[2] * gat_bias[2 * HD + e];
    acc0 += wb; acc1 += wb; acc2 += wb; acc3 += wb;
    acc4 += wb; acc5 += wb; acc6 += wb; acc7 += wb;

    size_t row = (size_t)n * BT + btg8 * 8;
    gatb[(row + 0) * HD + e] = f2bf(acc0);
    gatb[(row + 1) * HD + e] = f2bf(acc1);
    gatb[(row + 2) * HD + e] = f2bf(acc2);
    gatb[(row + 3) * HD + e] = f2bf(acc3);
    gatb[(row + 4) * HD + e] = f2bf(acc4);
    gatb[(row + 5) * HD + e] = f2bf(acc5);
    gatb[(row + 6) * HD + e] = f2bf(acc6);
    gatb[(row + 7) * HD + e] = f2bf(acc7);
}
#undef EFMA
#undef PHASE1
#undef PHASE2

// ---------------- merge via bf16 MFMA + leakyrelu + residual ----------------
__global__ __launch_bounds__(256) void merge_mfma_kernel(
    const unsigned short* __restrict__ gatb,
    const float* __restrict__ merge_w, const float* __restrict__ merge_b,
    const float* __restrict__ x, float* __restrict__ out)
{
    int m0 = blockIdx.x * 128;
    int t = threadIdx.x, w = t >> 6, l = t & 63;

    __shared__ __align__(16) unsigned short As[128 * 128]; // 32 KB, swz
    __shared__ __align__(16) unsigned short Bs[64 * 128];  // 16 KB, swz

    #pragma unroll
    for (int rep = 0; rep < 8; ++rep) {
        int gid = t + 256 * rep;       // 0..2047
        int row = gid >> 4, gg = gid & 15;
        uint4 v = *(const uint4*)((const char*)gatb + ((size_t)(m0 + row)) * 256 + gg * 16);
        *(uint4*)((char*)As + row * 256 + ((gg ^ (row & 15)) << 4)) = v;
    }
    #pragma unroll
    for (int rep = 0; rep < 4; ++rep) {
        int gid = t + 256 * rep;       // 0..1023
        int col = gid >> 4, gg = gid & 15;
        float v[8];
        #pragma unroll
        for (int jv = 0; jv < 8; ++jv)
            v[jv] = merge_w[(gg * 8 + jv) * DD + col];
        uint4 pk = { pack2(v[0], v[1]), pack2(v[2], v[3]),
                     pack2(v[4], v[5]), pack2(v[6], v[7]) };
        *(uint4*)((char*)Bs + col * 256 + ((gg ^ (col & 15)) << 4)) = pk;
    }
    __syncthreads();

    int Mw = (w & 1) * 64, Nw = (w >> 1) * 32;
    int rsel = l & 15, ksel = l >> 4;

    f4v acc[4][2];
    #pragma unroll
    for (int mi = 0; mi < 4; ++mi)
        #pragma unroll
        for (int nf = 0; nf < 2; ++nf)
            acc[mi][nf] = (f4v){0.f, 0.f, 0.f, 0.f};

    s8v af[4][4], bfr[2][4];
    #pragma unroll
    for (int mi = 0; mi < 4; ++mi)
        #pragma unroll
        for (int ks = 0; ks < 4; ++ks) {
            int row = Mw + mi * 16 + rsel;
            int g2 = ks * 4 + ksel;
            af[mi][ks] = *(const s8v*)((const char*)As + row * 256 + ((g2 ^ (row & 15)) << 4));
        }
    #pragma unroll
    for (int nf = 0; nf < 2; ++nf)
        #pragma unroll
        for (int ks = 0; ks < 4; ++ks) {
            int col = Nw + nf * 16 + rsel;
            int g2 = ks * 4 + ksel;
            bfr[nf][ks] = *(const s8v*)((const char*)Bs + col * 256 + ((g2 ^ (col & 15)) << 4));
        }

    #pragma unroll
    for (int mi = 0; mi < 4; ++mi)
        #pragma unroll
        for (int nf = 0; nf < 2; ++nf)
            #pragma unroll
            for (int ks = 0; ks < 4; ++ks)
                acc[mi][nf] = __builtin_amdgcn_mfma_f32_16x16x32_bf16(
                    af[mi][ks], bfr[nf][ks], acc[mi][nf], 0, 0, 0);

    int i0 = (l >> 4) * 4;
    #pragma unroll
    for (int mi = 0; mi < 4; ++mi) {
        int m = m0 + Mw + mi * 16 + i0;          // 4 rows, same n/b (4 | 12 | 48)
        int n = m / BT, btb = m - n * BT;
        int b = btb / TT, t0 = btb - b * TT;
        #pragma unroll
        for (int nf = 0; nf < 2; ++nf) {
            int dd = Nw + nf * 16 + (l & 15);
            float mb = merge_b[dd];
            #pragma unroll
            for (int reg = 0; reg < 4; ++reg) {
                float mg = acc[mi][nf][reg] + mb;
                mg = mg > 0.f ? mg : mg * 0.01f;
                size_t oidx = (((size_t)b * NN + n) * TT + t0 + reg) * DD + dd;
                out[oidx] = mg + x[oidx];
            }
        }
    }
}

extern "C" void kernel_launch(void* const* d_in, const int* in_sizes, int n_in,
                              void* d_out, int out_size, void* d_ws, size_t ws_size,
                              hipStream_t stream)
{
    const float* x        = (const float*)d_in[0];
    const float* fc_w     = (const float*)d_in[1];
    const float* attn_l   = (const float*)d_in[2];
    const float* attn_r   = (const float*)d_in[3];
    const float* gat_bias = (const float*)d_in[4];
    const float* weight   = (const float*)d_in[5];
    const float* merge_w  = (const float*)d_in[6];
    const float* merge_b  = (const float*)d_in[7];
    const int*   src_idx  = (const int*)d_in[8];
    const int*   dst_idx  = (const int*)d_in[9];
    float*       out      = (float*)d_out;

    char* p = (char*)d_ws;
    auto carve = [&](size_t bytes) { char* r = p; p += (bytes + 15) & ~size_t(15); return r; };
    uint4* featp   = (uint4*)carve(sizeof(uint4) * (size_t)NSL * NODES * 64);     // 37.8 MB
    unsigned short* gatb = (unsigned short*)carve(sizeof(unsigned short) * (size_t)NN * BT * HD); // 12.6 MB
    float* elp     = (float*)carve(sizeof(float) * (size_t)NSL * NODES * 8);      // 1.18 MB
    float* er      = (float*)carve(sizeof(float) * (size_t)KK * NN * BTH);
    float* alc     = (float*)carve(sizeof(float) * KK * HH * CC);
    float* arc     = (float*)carve(sizeof(float) * KK * HH * CC);
    int*   counts  = (int*)carve(sizeof(int) * KK * NN);
    int*   cursor  = (int*)carve(sizeof(int) * KK * NN);
    int4*  segs    = (int4*)carve(sizeof(int4) * NN);
    int*   csr_comb= (int*)carve(sizeof(int) * (CSR_CAP + 80));

    hipMemsetAsync(counts, 0, sizeof(int) * KK * NN, stream);

    aux_kernel<<<EDGE_BLOCKS + 1, 256, 0, stream>>>(
        dst_idx, counts, fc_w, attn_l, attn_r, alc, arc, featp, elp);

    scan_kernel<<<1, 1024, 0, stream>>>(counts, segs, cursor, csr_comb);

    feat_kernel<<<FEAT_BLOCKS, 256, 0, stream>>>(x, fc_w, featp);

    side_kernel<<<EDGE_BLOCKS + NN, 256, 0, stream>>>(
        src_idx, dst_idx, cursor, csr_comb, x, alc, arc, elp, er);

    agg_kernel<<<NSL * 256, 256, 0, stream>>>(
        featp, elp, er, segs, csr_comb, gat_bias, weight, gatb);

    merge_mfma_kernel<<<NN * BT / 128, 256, 0, stream>>>(gatb, merge_w, merge_b, x, out);
}

// Round 22
// 117.095 us; speedup vs baseline: 1.0300x; 1.0300x over previous
//
#include <hip/hip_runtime.h>

#define NN   1024
#define TT   12
#define CC   64
#define DD   64
#define HH   2
#define KK   3
#define ETOT 17408           // E (16384) + N self loops
#define BT   48              // B*T
#define BTH  96              // B*T*H
#define HD   128             // H*D
#define NODES (KK * NN + 1)  // +1 sentinel pad node (feat=0, el=-inf)
#define PADN  (KK * NN)
#define CSR_CAP (KK * ETOT + 12 * NN)   // segments padded to x4 (= 64512)
#define LOG2E 1.44269504f
#define MT   128                         // feat GEMM M-tile
#define NBLK (NN * BT / MT)              // 384 M-tiles
#define EDGE_BLOCKS ((KK * ETOT + 255) / 256)   // 204
#define FEAT_BLOCKS (KK * NBLK)                 // 1152
#define NSL  12                          // slices: (btg8 0..5) x (h 0..1)
#define RUNCAP 144                       // max combined padded run per n (~86 actual)

typedef __attribute__((ext_vector_type(8))) short s8v;    // 8 bf16
typedef __attribute__((ext_vector_type(4))) float f4v;    // 4 f32 acc

__device__ __forceinline__ float bf_lo(unsigned int u) {
    return __uint_as_float(u << 16);
}
__device__ __forceinline__ float bf_hi(unsigned int u) {
    return __uint_as_float(u & 0xFFFF0000u);
}
__device__ __forceinline__ unsigned short f2bf(float f) {
    unsigned int u = __float_as_uint(f);
    u += 0x7FFFu + ((u >> 16) & 1u);      // round-to-nearest-even
    return (unsigned short)(u >> 16);
}
__device__ __forceinline__ unsigned int pack2(float a, float b) {
    return (unsigned int)f2bf(a) | ((unsigned int)f2bf(b) << 16);
}
__device__ __forceinline__ float rlf(float v, int lane) {
    return __int_as_float(__builtin_amdgcn_readlane(__float_as_int(v), lane));
}

// ---------------- aux: count (blocks 0..203) + prep_alc + pad-init ----------
__global__ __launch_bounds__(256) void aux_kernel(
    const int* __restrict__ dst_idx, int* __restrict__ counts,
    const float* __restrict__ fc_w, const float* __restrict__ attn_l,
    const float* __restrict__ attn_r, float* __restrict__ alc, float* __restrict__ arc,
    uint4* __restrict__ featp, float* __restrict__ elp)
{
    int bid = blockIdx.x;
    int t = threadIdx.x;
    if (bid < EDGE_BLOCKS) {
        int tid = bid * 256 + t;
        if (tid < KK * ETOT) {
            int k = tid / ETOT;
            atomicAdd(&counts[k * NN + dst_idx[tid]], 1);
        }
    } else {
        for (int item = t; item < KK * HH * CC; item += 256) {   // prep_alc
            int kh = item >> 6, c = item & 63;
            int k = kh >> 1, h = kh & 1;
            float sl = 0.f, sr = 0.f;
            #pragma unroll
            for (int dd = 0; dd < 64; ++dd) {
                float wv = fc_w[k * CC * HD + c * HD + h * 64 + dd];
                sl = fmaf(wv, attn_l[k * HD + h * 64 + dd], sl);
                sr = fmaf(wv, attn_r[k * HD + h * 64 + dd], sr);
            }
            alc[item] = sl * LOG2E;
            arc[item] = sr * LOG2E;
        }
        for (int item = t; item < NSL * 64; item += 256)         // feat pad node
            featp[((size_t)(item >> 6) * NODES + PADN) * 64 + (item & 63)] =
                make_uint4(0u, 0u, 0u, 0u);
        for (int item = t; item < NSL * 8; item += 256)          // elp pad node
            elp[((size_t)(item >> 3) * NODES + PADN) * 8 + (item & 7)] = -1e30f;
    }
}

// ---------------- CSR scan (per-(k,n) segments, padded to 4) ----------------
__global__ __launch_bounds__(1024) void scan_kernel(
    const int* __restrict__ counts,
    int4* __restrict__ segs, int* __restrict__ cursor, int* __restrict__ csr_comb)
{
    int n = threadIdx.x;
    int c0 = counts[n], c1 = counts[NN + n], c2 = counts[2 * NN + n];
    int p0 = (c0 + 3) & ~3, p1 = (c1 + 3) & ~3, p2 = (c2 + 3) & ~3;
    int tot = p0 + p1 + p2;
    __shared__ int buf[NN];
    buf[n] = tot;
    __syncthreads();
    for (int off = 1; off < NN; off <<= 1) {
        int v = (n >= off) ? buf[n - off] : 0;
        __syncthreads();
        buf[n] += v;
        __syncthreads();
    }
    int excl = buf[n] - tot;
    int4 sg;
    sg.x = excl; sg.y = excl + p0; sg.z = excl + p0 + p1; sg.w = excl + tot;
    segs[n] = sg;
    cursor[n] = sg.x;
    cursor[NN + n] = sg.y;
    cursor[2 * NN + n] = sg.z;
    for (int j = sg.x + c0; j < sg.y; ++j) csr_comb[j] = PADN;
    for (int j = sg.y + c1; j < sg.z; ++j) csr_comb[j] = PADN;
    for (int j = sg.z + c2; j < sg.w; ++j) csr_comb[j] = PADN;
}

// ---------------- feat = x @ fc_w via bf16 MFMA (XCD-aware, k inner) --------
__global__ __launch_bounds__(256) void feat_kernel(
    const float* __restrict__ x, const float* __restrict__ fc_w,
    uint4* __restrict__ featp)
{
    int jj = ((int)blockIdx.x & 7) * (FEAT_BLOCKS / 8) + ((int)blockIdx.x >> 3);
    int mt = jj / KK;
    int k  = jj - mt * KK;
    int m0 = mt * MT;
    int t  = threadIdx.x;
    int w  = t >> 6, l = t & 63;

    __shared__ __align__(16) unsigned short As[128 * 64];  // 16 KB
    __shared__ __align__(16) unsigned short Ws[128 * 64];  // 16 KB

    #pragma unroll
    for (int rep = 0; rep < 4; ++rep) {
        int gid = t + 256 * rep;       // 0..1023
        int row = gid >> 3, g = gid & 7;
        int m = m0 + row;
        int n = m / BT, bt = m - n * BT;
        int b = bt / TT, tt2 = bt - b * TT;
        const float* xr = &x[(((size_t)b * NN + n) * TT + tt2) * CC + g * 8];
        float4 v0 = *(const float4*)xr;
        float4 v1 = *(const float4*)(xr + 4);
        uint4 pk = { pack2(v0.x, v0.y), pack2(v0.z, v0.w),
                     pack2(v1.x, v1.y), pack2(v1.z, v1.w) };
        *(uint4*)((char*)As + row * 128 + ((g ^ (row & 7)) << 4)) = pk;
    }
    #pragma unroll
    for (int rep = 0; rep < 4; ++rep) {
        int gid = t + 256 * rep;
        int e = gid & 127, g = gid >> 7;
        float v[8];
        #pragma unroll
        for (int jv = 0; jv < 8; ++jv)
            v[jv] = fc_w[(size_t)k * CC * HD + (g * 8 + jv) * HD + e];
        uint4 pk = { pack2(v[0], v[1]), pack2(v[2], v[3]),
                     pack2(v[4], v[5]), pack2(v[6], v[7]) };
        *(uint4*)((char*)Ws + e * 128 + ((g ^ (e & 7)) << 4)) = pk;
    }
    __syncthreads();

    int Mw = (w & 1) * 64;
    int Nw = (w >> 1) * 64;
    int rsel = l & 15, ksel = l >> 4;

    f4v acc[4][4];
    #pragma unroll
    for (int mi = 0; mi < 4; ++mi)
        #pragma unroll
        for (int nf = 0; nf < 4; ++nf)
            acc[mi][nf] = (f4v){0.f, 0.f, 0.f, 0.f};

    s8v af[4][2], bf[4][2];
    #pragma unroll
    for (int mi = 0; mi < 4; ++mi)
        #pragma unroll
        for (int ks = 0; ks < 2; ++ks) {
            int row = Mw + mi * 16 + rsel;
            int g = ks * 4 + ksel;
            af[mi][ks] = *(const s8v*)((const char*)As + row * 128 + ((g ^ (row & 7)) << 4));
        }
    #pragma unroll
    for (int nf = 0; nf < 4; ++nf)
        #pragma unroll
        for (int ks = 0; ks < 2; ++ks) {
            int e = Nw + nf * 16 + rsel;
            int g = ks * 4 + ksel;
            bf[nf][ks] = *(const s8v*)((const char*)Ws + e * 128 + ((g ^ (e & 7)) << 4));
        }

    #pragma unroll
    for (int mi = 0; mi < 4; ++mi)
        #pragma unroll
        for (int nf = 0; nf < 4; ++nf) {
            acc[mi][nf] = __builtin_amdgcn_mfma_f32_16x16x32_bf16(
                af[mi][0], bf[nf][0], acc[mi][nf], 0, 0, 0);
            acc[mi][nf] = __builtin_amdgcn_mfma_f32_16x16x32_bf16(
                af[mi][1], bf[nf][1], acc[mi][nf], 0, 0, 0);
        }

    // epilogue: combine partner frags (rows +0..3 / +4..7) into bt-octet
    int i0 = (l >> 4) * 4;
    bool writer = ((l >> 4) & 1) == 0;     // i0 in {0, 8}
    #pragma unroll
    for (int mi = 0; mi < 4; ++mi) {
        int m = m0 + Mw + mi * 16 + i0;    // octet base row for writer lanes
        int n = m / BT, bt = m - n * BT;
        #pragma unroll
        for (int nf = 0; nf < 4; ++nf) {
            uint2 o = { pack2(acc[mi][nf][0], acc[mi][nf][1]),
                        pack2(acc[mi][nf][2], acc[mi][nf][3]) };
            unsigned int px = (unsigned int)__shfl_xor((int)o.x, 16, 64);
            unsigned int py = (unsigned int)__shfl_xor((int)o.y, 16, 64);
            if (writer) {
                int e = Nw + nf * 16 + (l & 15);
                int h = e >> 6, d = e & 63;
                int s = ((bt >> 3) << 1) + h;
                featp[((size_t)s * NODES + k * NN + n) * 64 + d] =
                    make_uint4(o.x, o.y, px, py);
            }
        }
    }
}

// ---------------- side: scatter (0..203) | elr (204..1227) ------------------
__global__ __launch_bounds__(256) void side_kernel(
    const int* __restrict__ src_idx, const int* __restrict__ dst_idx,
    int* __restrict__ cursor, int* __restrict__ csr_comb,
    const float* __restrict__ x,
    const float* __restrict__ alc, const float* __restrict__ arc,
    float* __restrict__ elp, float* __restrict__ er)
{
    int bid = blockIdx.x;
    int t = threadIdx.x;

    if (bid < EDGE_BLOCKS) {
        int tid = bid * 256 + t;
        if (tid < KK * ETOT) {
            int k = tid / ETOT;
            int pos = atomicAdd(&cursor[k * NN + dst_idx[tid]], 1);
            csr_comb[pos] = k * NN + src_idx[tid];
        }
        return;
    }

    // elr: el/er tiny GEMV per n
    __shared__ float x_lds[BT * CC];       // 12 KB
    __shared__ float cl[KK * HH * CC];     // 1.5 KB
    __shared__ float cr[KK * HH * CC];     // 1.5 KB
    int n = bid - EDGE_BLOCKS;

    for (int i = t; i < BT * CC; i += 256) {
        int bt = i >> 6, c = i & 63;
        int b = bt / TT, tt = bt - b * TT;
        x_lds[i] = x[(((size_t)b * NN + n) * TT + tt) * CC + c];
    }
    for (int i = t; i < KK * HH * CC; i += 256) { cl[i] = alc[i]; cr[i] = arc[i]; }
    __syncthreads();

    if (t < BTH) {
        int hh = t / BT, bt = t - hh * BT;
        #pragma unroll
        for (int k = 0; k < KK; ++k) {
            const float* alp = &cl[(k * HH + hh) * CC];
            const float* arp = &cr[(k * HH + hh) * CC];
            float sl = 0.f, sr = 0.f;
            #pragma unroll
            for (int cc = 0; cc < CC; ++cc) {
                int c = (cc + bt) & 63;        // stagger: conflict-free
                float xv = x_lds[bt * CC + c];
                sl = fmaf(xv, alp[c], sl);
                sr = fmaf(xv, arp[c], sr);
            }
            int s = ((bt >> 3) << 1) + hh;
            elp[((size_t)s * NODES + k * NN + n) * 8 + (bt & 7)] = sl;
            er[((size_t)(k * NN + n)) * BTH + t] = sr;
        }
    }
}

// ---------------- agg: fused softmax + gather-sum, 12 slices, uint4 ---------
#define EFMA(F, LO, HI)                                        \
    r0 = fmaf((LO).x, bf_lo((F).x), r0);                       \
    r1 = fmaf((LO).y, bf_hi((F).x), r1);                       \
    r2 = fmaf((LO).z, bf_lo((F).y), r2);                       \
    r3 = fmaf((LO).w, bf_hi((F).y), r3);                       \
    r4 = fmaf((HI).x, bf_lo((F).z), r4);                       \
    r5 = fmaf((HI).y, bf_hi((F).z), r5);                       \
    r6 = fmaf((HI).z, bf_lo((F).w), r6);                       \
    r7 = fmaf((HI).w, bf_hi((F).w), r7);

#define PHASE1(JB, JE, KIDX, SCLO, SCHI) {                                     \
    int jb = (JB), je = (JE);                                                  \
    float erv = er[((size_t)((KIDX) * NN + n)) * BTH + h * BT + btg8 * 8 + btq];\
    float ss = 0.f;                                                            \
    for (int j0 = jb; j0 < je; j0 += 8) {                                      \
        int jjq = j0 + joff;                                                   \
        float a = 0.f;                                                         \
        if (jjq < je) {                                                        \
            int idx = csr_comb[jjq];                                           \
            float ev = elp[sbase8 + (size_t)idx * 8 + btq] + erv;              \
            ev = fmaxf(ev, ev * 0.2f);                                         \
            a = __builtin_amdgcn_exp2f(ev);                                    \
            alds[w][jjq - base0][btq] = a;                                     \
        }                                                                      \
        ss += a;                                                               \
    }                                                                          \
    ss += __shfl_xor(ss, 8, 64);                                               \
    ss += __shfl_xor(ss, 16, 64);                                              \
    ss += __shfl_xor(ss, 32, 64);                                              \
    float wk_ = weight[KIDX];                                                  \
    SCLO = make_float4(wk_ * __builtin_amdgcn_rcpf(rlf(ss, 0)),                \
                       wk_ * __builtin_amdgcn_rcpf(rlf(ss, 1)),                \
                       wk_ * __builtin_amdgcn_rcpf(rlf(ss, 2)),                \
                       wk_ * __builtin_amdgcn_rcpf(rlf(ss, 3)));               \
    SCHI = make_float4(wk_ * __builtin_amdgcn_rcpf(rlf(ss, 4)),                \
                       wk_ * __builtin_amdgcn_rcpf(rlf(ss, 5)),                \
                       wk_ * __builtin_amdgcn_rcpf(rlf(ss, 6)),                \
                       wk_ * __builtin_amdgcn_rcpf(rlf(ss, 7))); }

#define PHASE2(JB, JE, SCLO, SCHI) {                                           \
    int jb = __builtin_amdgcn_readfirstlane(JB);                               \
    int je = __builtin_amdgcn_readfirstlane(JE);                               \
    float r0=0.f,r1=0.f,r2=0.f,r3=0.f,r4=0.f,r5=0.f,r6=0.f,r7=0.f;             \
    for (int jjq = jb; jjq < je; jjq += 4) {                                   \
        int4 i4 = *(const int4*)&csr_comb[jjq];                                \
        int i0 = __builtin_amdgcn_readfirstlane(i4.x);                         \
        int i1 = __builtin_amdgcn_readfirstlane(i4.y);                         \
        int i2 = __builtin_amdgcn_readfirstlane(i4.z);                         \
        int i3 = __builtin_amdgcn_readfirstlane(i4.w);                         \
        uint4 f0 = fb[(size_t)i0 * 64];                                        \
        uint4 f1 = fb[(size_t)i1 * 64];                                        \
        uint4 f2 = fb[(size_t)i2 * 64];                                        \
        uint4 f3 = fb[(size_t)i3 * 64];                                        \
        float4 L0 = *(const float4*)&alds[w][jjq - base0 + 0][0];              \
        float4 H0 = *(const float4*)&alds[w][jjq - base0 + 0][4];              \
        float4 L1 = *(const float4*)&alds[w][jjq - base0 + 1][0];              \
        float4 H1 = *(const float4*)&alds[w][jjq - base0 + 1][4];              \
        float4 L2 = *(const float4*)&alds[w][jjq - base0 + 2][0];              \
        float4 H2 = *(const float4*)&alds[w][jjq - base0 + 2][4];              \
        float4 L3 = *(const float4*)&alds[w][jjq - base0 + 3][0];              \
        float4 H3 = *(const float4*)&alds[w][jjq - base0 + 3][4];              \
        EFMA(f0, L0, H0); EFMA(f1, L1, H1);                                    \
        EFMA(f2, L2, H2); EFMA(f3, L3, H3);                                    \
    }                                                                          \
    acc0 = fmaf(r0, (SCLO).x, acc0); acc1 = fmaf(r1, (SCLO).y, acc1);          \
    acc2 = fmaf(r2, (SCLO).z, acc2); acc3 = fmaf(r3, (SCLO).w, acc3);          \
    acc4 = fmaf(r4, (SCHI).x, acc4); acc5 = fmaf(r5, (SCHI).y, acc5);          \
    acc6 = fmaf(r6, (SCHI).z, acc6); acc7 = fmaf(r7, (SCHI).w, acc7); }

__global__ __launch_bounds__(256) void agg_kernel(
    const uint4* __restrict__ featp,
    const float* __restrict__ elp,
    const float* __restrict__ er,
    const int4* __restrict__ segs, const int* __restrict__ csr_comb,
    const float* __restrict__ gat_bias, const float* __restrict__ weight,
    unsigned short* __restrict__ gatb)   // [n*BT+bt][HD] bf16
{
    int xcd = (int)blockIdx.x & 7;
    int q   = (int)blockIdx.x >> 3;      // 0..383
    int j   = q + 384 * xcd;             // 0..3071
    int s   = j >> 8;                    // 0..11
    int g   = j & 255;
    int w = threadIdx.x >> 6;
    int l = threadIdx.x & 63;
    int n = g * 4 + w;
    int btg8 = s >> 1, h = s & 1;
    int e = h * 64 + l;

    __shared__ __align__(16) float alds[4][RUNCAP][8];   // 18.4 KB

    const uint4* fb = featp + (size_t)s * NODES * 64 + l;
    size_t sbase8 = (size_t)s * NODES * 8;
    int4 sg = segs[n];
    int base0 = __builtin_amdgcn_readfirstlane(sg.x);

    int joff = l >> 3, btq = l & 7;
    float acc0=0.f,acc1=0.f,acc2=0.f,acc3=0.f,acc4=0.f,acc5=0.f,acc6=0.f,acc7=0.f;
    float4 sclo, schi;

    PHASE1(sg.x, sg.y, 0, sclo, schi)
    PHASE2(sg.x, sg.y, sclo, schi)
    PHASE1(sg.y, sg.z, 1, sclo, schi)
    PHASE2(sg.y, sg.z, sclo, schi)
    PHASE1(sg.z, sg.w, 2, sclo, schi)
    PHASE2(sg.z, sg.w, sclo, schi)

    float wb = weight[0] * gat_bias[e] + weight[1] * gat_bias[HD + e]
             + weight[2] * gat_bias[2 * HD + e];
    acc0 += wb; acc1 += wb; acc2 += wb; acc3 += wb;
    acc4 += wb; acc5 += wb; acc6 += wb; acc7 += wb;

    size_t row = (size_t)n * BT + btg8 * 8;
    gatb[(row + 0) * HD + e] = f2bf(acc0);
    gatb[(row + 1) * HD + e] = f2bf(acc1);
    gatb[(row + 2) * HD + e] = f2bf(acc2);
    gatb[(row + 3) * HD + e] = f2bf(acc3);
    gatb[(row + 4) * HD + e] = f2bf(acc4);
    gatb[(row + 5) * HD + e] = f2bf(acc5);
    gatb[(row + 6) * HD + e] = f2bf(acc6);
    gatb[(row + 7) * HD + e] = f2bf(acc7);
}
#undef EFMA
#undef PHASE1
#undef PHASE2

// ---------------- merge via bf16 MFMA + leakyrelu + residual ----------------
__global__ __launch_bounds__(256) void merge_mfma_kernel(
    const unsigned short* __restrict__ gatb,
    const float* __restrict__ merge_w, const float* __restrict__ merge_b,
    const float* __restrict__ x, float* __restrict__ out)
{
    int m0 = blockIdx.x * 128;
    int t = threadIdx.x, w = t >> 6, l = t & 63;

    __shared__ __align__(16) unsigned short As[128 * 128]; // 32 KB, swz
    __shared__ __align__(16) unsigned short Bs[64 * 128];  // 16 KB, swz

    #pragma unroll
    for (int rep = 0; rep < 8; ++rep) {
        int gid = t + 256 * rep;       // 0..2047
        int row = gid >> 4, gg = gid & 15;
        uint4 v = *(const uint4*)((const char*)gatb + ((size_t)(m0 + row)) * 256 + gg * 16);
        *(uint4*)((char*)As + row * 256 + ((gg ^ (row & 15)) << 4)) = v;
    }
    #pragma unroll
    for (int rep = 0; rep < 4; ++rep) {
        int gid = t + 256 * rep;       // 0..1023
        int col = gid >> 4, gg = gid & 15;
        float v[8];
        #pragma unroll
        for (int jv = 0; jv < 8; ++jv)
            v[jv] = merge_w[(gg * 8 + jv) * DD + col];
        uint4 pk = { pack2(v[0], v[1]), pack2(v[2], v[3]),
                     pack2(v[4], v[5]), pack2(v[6], v[7]) };
        *(uint4*)((char*)Bs + col * 256 + ((gg ^ (col & 15)) << 4)) = pk;
    }
    __syncthreads();

    int Mw = (w & 1) * 64, Nw = (w >> 1) * 32;
    int rsel = l & 15, ksel = l >> 4;

    f4v acc[4][2];
    #pragma unroll
    for (int mi = 0; mi < 4; ++mi)
        #pragma unroll
        for (int nf = 0; nf < 2; ++nf)
            acc[mi][nf] = (f4v){0.f, 0.f, 0.f, 0.f};

    s8v af[4][4], bfr[2][4];
    #pragma unroll
    for (int mi = 0; mi < 4; ++mi)
        #pragma unroll
        for (int ks = 0; ks < 4; ++ks) {
            int row = Mw + mi * 16 + rsel;
            int g2 = ks * 4 + ksel;
            af[mi][ks] = *(const s8v*)((const char*)As + row * 256 + ((g2 ^ (row & 15)) << 4));
        }
    #pragma unroll
    for (int nf = 0; nf < 2; ++nf)
        #pragma unroll
        for (int ks = 0; ks < 4; ++ks) {
            int col = Nw + nf * 16 + rsel;
            int g2 = ks * 4 + ksel;
            bfr[nf][ks] = *(const s8v*)((const char*)Bs + col * 256 + ((g2 ^ (col & 15)) << 4));
        }

    #pragma unroll
    for (int mi = 0; mi < 4; ++mi)
        #pragma unroll
        for (int nf = 0; nf < 2; ++nf)
            #pragma unroll
            for (int ks = 0; ks < 4; ++ks)
                acc[mi][nf] = __builtin_amdgcn_mfma_f32_16x16x32_bf16(
                    af[mi][ks], bfr[nf][ks], acc[mi][nf], 0, 0, 0);

    int i0 = (l >> 4) * 4;
    #pragma unroll
    for (int mi = 0; mi < 4; ++mi) {
        int m = m0 + Mw + mi * 16 + i0;          // 4 rows, same n/b (4 | 12 | 48)
        int n = m / BT, btb = m - n * BT;
        int b = btb / TT, t0 = btb - b * TT;
        #pragma unroll
        for (int nf = 0; nf < 2; ++nf) {
            int dd = Nw + nf * 16 + (l & 15);
            float mb = merge_b[dd];
            #pragma unroll
            for (int reg = 0; reg < 4; ++reg) {
                float mg = acc[mi][nf][reg] + mb;
                mg = mg > 0.f ? mg : mg * 0.01f;
                size_t oidx = (((size_t)b * NN + n) * TT + t0 + reg) * DD + dd;
                out[oidx] = mg + x[oidx];
            }
        }
    }
}

extern "C" void kernel_launch(void* const* d_in, const int* in_sizes, int n_in,
                              void* d_out, int out_size, void* d_ws, size_t ws_size,
                              hipStream_t stream)
{
    const float* x        = (const float*)d_in[0];
    const float* fc_w     = (const float*)d_in[1];
    const float* attn_l   = (const float*)d_in[2];
    const float* attn_r   = (const float*)d_in[3];
    const float* gat_bias = (const float*)d_in[4];
    const float* weight   = (const float*)d_in[5];
    const float* merge_w  = (const float*)d_in[6];
    const float* merge_b  = (const float*)d_in[7];
    const int*   src_idx  = (const int*)d_in[8];
    const int*   dst_idx  = (const int*)d_in[9];
    float*       out      = (float*)d_out;

    char* p = (char*)d_ws;
    auto carve = [&](size_t bytes) { char* r = p; p += (bytes + 15) & ~size_t(15); return r; };
    uint4* featp   = (uint4*)carve(sizeof(uint4) * (size_t)NSL * NODES * 64);     // 37.8 MB
    unsigned short* gatb = (unsigned short*)carve(sizeof(unsigned short) * (size_t)NN * BT * HD); // 12.6 MB
    float* elp     = (float*)carve(sizeof(float) * (size_t)NSL * NODES * 8);      // 1.18 MB
    float* er      = (float*)carve(sizeof(float) * (size_t)KK * NN * BTH);
    float* alc     = (float*)carve(sizeof(float) * KK * HH * CC);
    float* arc     = (float*)carve(sizeof(float) * KK * HH * CC);
    int*   counts  = (int*)carve(sizeof(int) * KK * NN);
    int*   cursor  = (int*)carve(sizeof(int) * KK * NN);
    int4*  segs    = (int4*)carve(sizeof(int4) * NN);
    int*   csr_comb= (int*)carve(sizeof(int) * (CSR_CAP + 80));

    hipMemsetAsync(counts, 0, sizeof(int) * KK * NN, stream);

    aux_kernel<<<EDGE_BLOCKS + 1, 256, 0, stream>>>(
        dst_idx, counts, fc_w, attn_l, attn_r, alc, arc, featp, elp);

    scan_kernel<<<1, 1024, 0, stream>>>(counts, segs, cursor, csr_comb);

    feat_kernel<<<FEAT_BLOCKS, 256, 0, stream>>>(x, fc_w, featp);

    side_kernel<<<EDGE_BLOCKS + NN, 256, 0, stream>>>(
        src_idx, dst_idx, cursor, csr_comb, x, alc, arc, elp, er);

    agg_kernel<<<NSL * 256, 256, 0, stream>>>(
        featp, elp, er, segs, csr_comb, gat_bias, weight, gatb);

    merge_mfma_kernel<<<NN * BT / 128, 256, 0, stream>>>(gatb, merge_w, merge_b, x, out);
}